// Round 4
// baseline (268.691 us; speedup 1.0000x reference)
//
#include <hip/hip_runtime.h>
#include <stdint.h>

#define NN 50000
#define NE 600000
#define DD 128
#define BN_EPS 1e-5f

typedef __attribute__((ext_vector_type(8))) short short8;
typedef __attribute__((ext_vector_type(4))) float f32x4;

__device__ __forceinline__ float bf2f(uint16_t u) {
    union { uint32_t u; float f; } v; v.u = ((uint32_t)u) << 16; return v.f;
}
__device__ __forceinline__ uint16_t f2bf(float f) {
    union { float f; uint32_t u; } v; v.f = f;
    return (uint16_t)((v.u + 0x7FFFu + ((v.u >> 16) & 1u)) >> 16);
}
__device__ __forceinline__ float lo16(uint32_t v) { return bf2f((uint16_t)(v & 0xFFFFu)); }
__device__ __forceinline__ float hi16(uint32_t v) { return bf2f((uint16_t)(v >> 16)); }

// ---------------- zero-init (replaces hipMemsetAsync) ----------------
// Zeroes ZLEN bytes at ws start (cnt + cursor + st0 + st1), vectorized.
__global__ void k_zero(uint4* __restrict__ p, int n16) {
    int i = blockIdx.x * 256 + threadIdx.x;
    if (i < n16) p[i] = make_uint4(0u, 0u, 0u, 0u);
}

// ---------------- CSR build ----------------
__global__ void k_count(const int* __restrict__ col, int* __restrict__ cnt) {
    int e = blockIdx.x * 256 + threadIdx.x;
    if (e < NE) atomicAdd(&cnt[col[e]], 1);
}

// Per node: segment base via wave-scan + one cursor atomic per wave.
__global__ void k_alloc(const int* __restrict__ cnt, int* __restrict__ cursor,
                        int* __restrict__ off, int* __restrict__ fillp,
                        float* __restrict__ deginv, float* __restrict__ dis) {
    int i = blockIdx.x * 256 + threadIdx.x;
    int lane = threadIdx.x & 63;
    int deg = (i < NN) ? cnt[i] : 0;
    int v = deg;
    #pragma unroll
    for (int d = 1; d < 64; d <<= 1) {
        int t = __shfl_up(v, d, 64);
        if (lane >= d) v += t;
    }
    int total = __shfl(v, 63, 64);
    int wbase = 0;
    if (lane == 63) wbase = atomicAdd(cursor, total);
    wbase = __shfl(wbase, 63, 64);
    int base = wbase + v - deg;   // exclusive prefix within wave + wave base
    if (i < NN) {
        off[i] = base;
        fillp[i] = base;
        deginv[i] = 1.0f / fmaxf((float)deg, 1.0f);   // ClusterGCN 1/deg
        dis[i] = rsqrtf((float)deg + 1.0f);           // SGConv D^{-1/2} incl self-loop
    }
}

__global__ void k_fill(const int* __restrict__ ei, int* __restrict__ fillp,
                       int* __restrict__ csr_row) {
    int e = blockIdx.x * 256 + threadIdx.x;
    if (e < NE) {
        int c = ei[NE + e];
        int p = atomicAdd(&fillp[c], 1);
        csr_row[p] = ei[e];
    }
}

// ---------------- gather + fp32->bf16 ----------------
__global__ void k_gather(const int* __restrict__ x_idx, const float* __restrict__ emb,
                         uint16_t* __restrict__ xb) {
    int idx = blockIdx.x * 256 + threadIdx.x;  // NN*32 threads, 4 elems each
    if (idx >= NN * 32) return;
    int node = idx >> 5, c4 = (idx & 31) << 2;
    int src = x_idx[node];
    float4 v = *(const float4*)(emb + (size_t)src * DD + c4);
    ushort4 o;
    o.x = f2bf(v.x); o.y = f2bf(v.y); o.z = f2bf(v.z); o.w = f2bf(v.w);
    *(ushort4*)(xb + (size_t)node * DD + c4) = o;
}

// ---------------- aggregation (1 wave = 1 node, exact count, 8/4/1 MLP) ----------------
// MODE 0: agg[c] = deginv[c] * sum_e x[row_e]
// MODE 1: agg[c] = dis[c] * (xs[c] + sum_e xs[row_e]), xs pre-scaled by dis on producer
template<int MODE>
__global__ __launch_bounds__(256)
void k_agg(const uint16_t* __restrict__ xb, const int* __restrict__ off,
           const int* __restrict__ cnt, const int* __restrict__ csr_row,
           const float* __restrict__ deginv, const float* __restrict__ dis,
           uint16_t* __restrict__ aggb) {
    int node = blockIdx.x * 4 + (threadIdx.x >> 6);
    if (node >= NN) return;
    int lane = threadIdx.x & 63;
    const uint32_t* __restrict__ xw = (const uint32_t*)xb;
    float a0 = 0.0f, a1 = 0.0f;
    if (MODE == 1) {
        uint32_t v = xw[(size_t)node * 64 + lane];  // self term: xs[c]
        a0 = lo16(v); a1 = hi16(v);
    }
    int s = off[node], e = s + cnt[node];
    for (int base = s; base < e; base += 64) {
        int c64 = min(e - base, 64);
        int idxv = (lane < c64) ? csr_row[base + lane] : 0;
        int i = 0;
        for (; i + 8 <= c64; i += 8) {
            uint32_t v[8];
            #pragma unroll
            for (int u = 0; u < 8; ++u) {
                int r = __builtin_amdgcn_readlane(idxv, i + u);
                v[u] = xw[(size_t)r * 64 + lane];
            }
            #pragma unroll
            for (int u = 0; u < 8; ++u) { a0 += lo16(v[u]); a1 += hi16(v[u]); }
        }
        if (i + 4 <= c64) {
            uint32_t v[4];
            #pragma unroll
            for (int u = 0; u < 4; ++u) {
                int r = __builtin_amdgcn_readlane(idxv, i + u);
                v[u] = xw[(size_t)r * 64 + lane];
            }
            #pragma unroll
            for (int u = 0; u < 4; ++u) { a0 += lo16(v[u]); a1 += hi16(v[u]); }
            i += 4;
        }
        for (; i < c64; ++i) {
            int r = __builtin_amdgcn_readlane(idxv, i);
            uint32_t v = xw[(size_t)r * 64 + lane];
            a0 += lo16(v); a1 += hi16(v);
        }
    }
    float sc = (MODE == 1) ? dis[node] : deginv[node];
    a0 *= sc; a1 *= sc;
    uint32_t o = (uint32_t)f2bf(a0) | ((uint32_t)f2bf(a1) << 16);
    *(uint32_t*)(aggb + (size_t)node * DD + lane * 2) = o;
}

// ---------------- MFMA GEMM: H = A1@W1^T (+ A2@W2^T) (+bias), BN stats ----------------
template<bool DUAL, bool STATS, bool BIAS, bool STORE_BF16>
__global__ __launch_bounds__(256, 2)
void k_gemm(const uint16_t* __restrict__ A1, const uint16_t* __restrict__ A2,
            const float* __restrict__ W1, const float* __restrict__ W2,
            const float* __restrict__ bias, float* __restrict__ Hf,
            uint16_t* __restrict__ Hb, float* __restrict__ stats) {
    __shared__ uint16_t Alds[128 * 128];
    __shared__ uint16_t Wlds[128 * 128];
    const int t = threadIdx.x;
    const int lane = t & 63, wid = t >> 6;
    const int wm = (wid >> 1) * 64, wn = (wid & 1) * 64;
    const int m0 = blockIdx.x * 128;
    f32x4 zero = {0.0f, 0.0f, 0.0f, 0.0f};
    f32x4 acc[4][4];
    #pragma unroll
    for (int m = 0; m < 4; ++m)
        #pragma unroll
        for (int n = 0; n < 4; ++n) acc[m][n] = zero;

    const int NP = DUAL ? 2 : 1;
    for (int p = 0; p < NP; ++p) {
        const uint16_t* A = (DUAL && p) ? A2 : A1;
        const float* W = (DUAL && p) ? W2 : W1;
        if (p) __syncthreads();
        #pragma unroll
        for (int it = 0; it < 8; ++it) {
            int idx = it * 256 + t;
            int row = idx >> 4, c16 = idx & 15;
            uint32_t boff = (uint32_t)(row * 256 + ((c16 * 16) ^ ((row & 7) << 4)));
            uint4 v = make_uint4(0u, 0u, 0u, 0u);
            if (m0 + row < NN)
                v = *(const uint4*)(A + (size_t)(m0 + row) * DD + c16 * 8);
            *(uint4*)((char*)Alds + boff) = v;
        }
        #pragma unroll
        for (int it = 0; it < 8; ++it) {
            int idx = it * 256 + t;
            int row = idx >> 4, c8 = idx & 15;
            const float* wp = W + row * DD + c8 * 8;
            float4 v0 = *(const float4*)(wp);
            float4 v1 = *(const float4*)(wp + 4);
            uint4 pk;
            pk.x = (uint32_t)f2bf(v0.x) | ((uint32_t)f2bf(v0.y) << 16);
            pk.y = (uint32_t)f2bf(v0.z) | ((uint32_t)f2bf(v0.w) << 16);
            pk.z = (uint32_t)f2bf(v1.x) | ((uint32_t)f2bf(v1.y) << 16);
            pk.w = (uint32_t)f2bf(v1.z) | ((uint32_t)f2bf(v1.w) << 16);
            uint32_t boff = (uint32_t)(row * 256 + ((c8 * 16) ^ ((row & 7) << 4)));
            *(uint4*)((char*)Wlds + boff) = pk;
        }
        __syncthreads();
        #pragma unroll
        for (int ks = 0; ks < 4; ++ks) {
            short8 a[4], b[4];
            int kb = ks * 64 + ((lane >> 4) << 4);
            #pragma unroll
            for (int m = 0; m < 4; ++m) {
                int row = wm + m * 16 + (lane & 15);
                a[m] = *(const short8*)((const char*)Alds + row * 256 + (kb ^ ((row & 7) << 4)));
            }
            #pragma unroll
            for (int n = 0; n < 4; ++n) {
                int row = wn + n * 16 + (lane & 15);
                b[n] = *(const short8*)((const char*)Wlds + row * 256 + (kb ^ ((row & 7) << 4)));
            }
            #pragma unroll
            for (int m = 0; m < 4; ++m)
                #pragma unroll
                for (int n = 0; n < 4; ++n)
                    acc[m][n] = __builtin_amdgcn_mfma_f32_16x16x32_bf16(a[m], b[n], acc[m][n], 0, 0, 0);
        }
    }
    #pragma unroll
    for (int n = 0; n < 4; ++n) {
        int col = wn + n * 16 + (lane & 15);
        float bb = BIAS ? bias[col] : 0.0f;
        float ssum = 0.0f, ssq = 0.0f;
        #pragma unroll
        for (int m = 0; m < 4; ++m) {
            int rbase = m0 + wm + m * 16 + ((lane >> 4) << 2);
            #pragma unroll
            for (int i = 0; i < 4; ++i) {
                int gr = rbase + i;
                if (gr < NN) {
                    float v = acc[m][n][i] + bb;
                    if (STORE_BF16) Hb[(size_t)gr * DD + col] = f2bf(v);
                    else            Hf[(size_t)gr * DD + col] = v;
                    ssum += v; ssq += v * v;
                }
            }
        }
        if (STATS) {
            ssum += __shfl_xor(ssum, 16, 64);
            ssum += __shfl_xor(ssum, 32, 64);
            ssq  += __shfl_xor(ssq, 16, 64);
            ssq  += __shfl_xor(ssq, 32, 64);
            if (lane < 16) {
                atomicAdd(&stats[col], ssum);
                atomicAdd(&stats[DD + col], ssq);
            }
        }
    }
}

// ---------------- fused BN prep + apply + ReLU + dis pre-scale ----------------
__global__ __launch_bounds__(256)
void k_bnrelu(const uint16_t* __restrict__ Hb, const float* __restrict__ st,
              const float* __restrict__ gamma, const float* __restrict__ beta,
              const float* __restrict__ dis, uint16_t* __restrict__ xb) {
    __shared__ float s_sc[128], s_of[128];
    int t = threadIdx.x;
    if (t < 128) {
        const float invn = 1.0f / (float)NN;
        float mean = st[t] * invn;
        float var = st[DD + t] * invn - mean * mean;
        float sc = gamma[t] * rsqrtf(var + BN_EPS);
        s_sc[t] = sc;
        s_of[t] = beta[t] - mean * sc;
    }
    __syncthreads();
    int idx = blockIdx.x * 256 + t;              // 16 threads/row, 8 elems/thread
    int node = idx >> 4, c8 = (idx & 15) << 3;
    if (node >= NN) return;
    float d = dis[node];
    uint4 h = *(const uint4*)(Hb + (size_t)node * DD + c8);
    uint32_t hw[4] = {h.x, h.y, h.z, h.w};
    uint32_t ow[4];
    #pragma unroll
    for (int j = 0; j < 4; ++j) {
        int c = c8 + j * 2;
        float v0 = fmaxf(lo16(hw[j]) * s_sc[c]     + s_of[c],     0.0f) * d;
        float v1 = fmaxf(hi16(hw[j]) * s_sc[c + 1] + s_of[c + 1], 0.0f) * d;
        ow[j] = (uint32_t)f2bf(v0) | ((uint32_t)f2bf(v1) << 16);
    }
    uint4 o = make_uint4(ow[0], ow[1], ow[2], ow[3]);
    *(uint4*)(xb + (size_t)node * DD + c8) = o;
}

// ---------------- launch ----------------
extern "C" void kernel_launch(void* const* d_in, const int* in_sizes, int n_in,
                              void* d_out, int out_size, void* d_ws, size_t ws_size,
                              hipStream_t stream) {
    const int* x_idx   = (const int*)d_in[0];
    const int* ei      = (const int*)d_in[1];
    const float* emb   = (const float*)d_in[2];
    const float* W_out = (const float*)d_in[3];
    const float* W_root= (const float*)d_in[4];
    const float* g0    = (const float*)d_in[5];
    const float* be0   = (const float*)d_in[6];
    const float* W1    = (const float*)d_in[7];
    const float* b1    = (const float*)d_in[8];
    const float* g1    = (const float*)d_in[9];
    const float* be1   = (const float*)d_in[10];
    const float* W2    = (const float*)d_in[11];
    const float* b2    = (const float*)d_in[12];
    float* out = (float*)d_out;

    char* ws = (char*)d_ws;
    size_t o = 0;
    auto carve = [&](size_t bytes) -> void* {
        void* p = ws + o;
        o = (o + bytes + 255) & ~(size_t)255;
        return p;
    };
    // zero-init group first (single k_zero pass)
    int* cnt      = (int*)carve((size_t)NN * 4);
    int* cursor   = (int*)carve(4);
    float* st0    = (float*)carve(256 * 4);
    float* st1    = (float*)carve(256 * 4);
    size_t zlen = o;                             // multiple of 256
    // rest
    int* fillp    = (int*)carve((size_t)NN * 4);
    int* off      = (int*)carve((size_t)NN * 4);
    float* deginv = (float*)carve((size_t)NN * 4);
    float* dis    = (float*)carve((size_t)NN * 4);
    int* csr_row  = (int*)carve((size_t)NE * 4);
    uint16_t* xb  = (uint16_t*)carve((size_t)NN * DD * 2);
    uint16_t* aggb= (uint16_t*)carve((size_t)NN * DD * 2);
    uint16_t* hb  = (uint16_t*)carve((size_t)NN * DD * 2);

    const int ZB = (int)((zlen / 16 + 255) / 256);
    const int EB = (NE + 255) / 256;
    const int NB = (NN + 255) / 256;            // 196
    const int GB = (NN + 127) / 128;            // 391 GEMM tiles
    const int AB = (NN + 3) / 4;                // 12500 agg blocks
    const int VB = (NN * 32 + 255) / 256;       // gather blocks
    const int BB = (NN * 16 + 255) / 256;       // 3125 bnrelu blocks

    k_zero<<<ZB, 256, 0, stream>>>((uint4*)ws, (int)(zlen / 16));
    k_count<<<EB, 256, 0, stream>>>(ei + NE, cnt);
    k_alloc<<<NB, 256, 0, stream>>>(cnt, cursor, off, fillp, deginv, dis);
    k_fill<<<EB, 256, 0, stream>>>(ei, fillp, csr_row);
    k_gather<<<VB, 256, 0, stream>>>(x_idx, emb, xb);

    // layer 0: ClusterGCN -> BN -> ReLU (bnrelu output pre-scaled by dis)
    k_agg<0><<<AB, 256, 0, stream>>>(xb, off, cnt, csr_row, deginv, dis, aggb);
    k_gemm<true, true, false, true><<<GB, 256, 0, stream>>>(
        aggb, xb, W_out, W_root, nullptr, nullptr, hb, st0);
    k_bnrelu<<<BB, 256, 0, stream>>>(hb, st0, g0, be0, dis, xb);

    // layer 1: SGConv -> BN -> ReLU (input xb is pre-scaled xs)
    k_agg<1><<<AB, 256, 0, stream>>>(xb, off, cnt, csr_row, deginv, dis, aggb);
    k_gemm<false, true, true, true><<<GB, 256, 0, stream>>>(
        aggb, nullptr, W1, nullptr, b1, nullptr, hb, st1);
    k_bnrelu<<<BB, 256, 0, stream>>>(hb, st1, g1, be1, dis, xb);

    // layer 2: final SGConv -> d_out (fp32)
    k_agg<1><<<AB, 256, 0, stream>>>(xb, off, cnt, csr_row, deginv, dis, aggb);
    k_gemm<false, false, true, false><<<GB, 256, 0, stream>>>(
        aggb, nullptr, W2, nullptr, b2, out, nullptr, nullptr);
}